// Round 7
// baseline (1600.750 us; speedup 1.0000x reference)
//
#include <hip/hip_runtime.h>

// GeneralConv_30820685316781 — f32 build, round 7: aggk->gemmbd+powmode-gemmt, qtr->gemmbd
#define N_ 40000
#define E_ 320000
#define D_ 128
#define H_ 4
#define T_ 3
#define R_ 5

typedef unsigned short u16;

__device__ __forceinline__ float bf2f(u16 h){ return __uint_as_float(((unsigned)h)<<16); }
__device__ __forceinline__ u16 f2bf(float f){
  unsigned u = __float_as_uint(f);
  u += 0x7fffu + ((u>>16)&1u);     // RNE
  return (u16)(u>>16);
}
__device__ __forceinline__ unsigned fmono(float f){
  unsigned u = __float_as_uint(f);
  return (u>>31) ? ~u : (u | 0x80000000u);
}
__device__ __forceinline__ float monof(unsigned u){
  return (u>>31) ? __uint_as_float(u & 0x7fffffffu) : __uint_as_float(~u);
}
__device__ __forceinline__ float ldx(const void* p, long i, int f32){
  return f32 ? ((const float*)p)[i] : bf2f(((const u16*)p)[i]);
}
__device__ __forceinline__ float wredsum(float v){
  #pragma unroll
  for (int m=32;m;m>>=1) v += __shfl_xor(v, m, 64);
  return v;
}

// wcf element offsets (f32 canonical weight buffer)
#define W_QW 0
#define W_KW 49152
#define W_VW 98304
#define W_AW 147456
#define W_QB 196608
#define W_KB 196992
#define W_VB 197376
#define W_AB 197760
#define W_PRI 198144
#define W_RATT 198164
#define W_RMSG 218644
#define W_WMK 239124
#define W_WAK 288276
#define W_WQ 337428
#define W_BQ 353812
#define W_WKL 353940
#define W_BKL 370324
#define W_SKIP 370452
#define W_LNG 370455
#define W_LNB 370839
#define W_TOT 371223

// ---- workspace layout (bytes). Peak 115,248,640 (= round-6 proven). ----
#define OFF_FLAGS 0ul
#define OFF_WCF   512ul
#define OFF_NT32  1485824ul
#define OFF_EI32  1646080ul
#define OFF_ET32  4206592ul
#define OFF_PERM  5486592ul    // node perm: 40192 ints, 64-aligned type groups, -1 pad
#define OFF_PCNT  5647360ul    // pcnt[12] | pc2[16] at +128
#define OFF_TVAL  5647872ul    // raT (80KB, s1-s6) ; nperm at +90112 (s0.8-s7.5) ; satt (s7.75-s8) ; tval (s9-s10)
#define OFF_NPERM 5737984ul    // 40320 ints (edge-type-sorted first-N edges)
#define OFF_LOG   6288384ul    // logits 5.12M | mxkey .64M | sumex .64M | deg .16M ; MT+ck overlay after satt
#define OFF_QN    12848640ul   // qn -> ag0 -> trans
#define OFF_KN    33328640ul   // kn -> ag1
#define OFF_VN    53808640ul   // vn -> ag2
#define OFF_QLIN  74288640ul   // qlin -> hbuf
#define OFF_QTR   94768640ul   // qtrb (s6) -> vp (s7.5-s8)

// ---------------------------------------------------------------------------
__global__ __launch_bounds__(256) void detect_kernel(
    const u16* __restrict__ xs, const int* __restrict__ nt, int* __restrict__ flags)
{
  __shared__ int sBig, sZero, sNz;
  int tid = threadIdx.x;
  if (tid==0){ sBig=0; sZero=0; sNz=0; }
  __syncthreads();
  int big=0, zc=0;
  for (int i=tid; i<1024; i+=256) {
    u16 v = xs[2*i];
    int e = (v>>7)&0xFF;
    big += (e >= 200);
    zc  += (v == 0);
  }
  int nz=0;
  for (int i=tid; i<1024; i+=256) nz += (nt[2*i+1] != 0);
  atomicAdd(&sBig, big); atomicAdd(&sZero, zc); atomicAdd(&sNz, nz);
  __syncthreads();
  if (tid==0) {
    flags[0] = (sBig > 64) || (sZero > 900);
    flags[1] = (sNz == 0);
  }
}

struct FPtrs { const void* p[20]; };
__global__ __launch_bounds__(256) void convf_kernel(
    const int* __restrict__ flags, FPtrs ptrs, float* __restrict__ wcf)
{
  const int start[21] = {0,49152,98304,147456,196608,196992,197376,197760,198144,
    198164,218644,239124,288276,337428,353812,353940,370324,370452,370455,370839,371223};
  int i = blockIdx.x*256 + threadIdx.x;
  if (i >= W_TOT) return;
  int arr = 0;
  #pragma unroll
  for (int a=1; a<20; ++a) arr += (i >= start[a]);
  int local = i - start[arr];
  wcf[i] = ldx(ptrs.p[arr], local, flags[0]);
}

__global__ __launch_bounds__(256) void idxconv_kernel(
    const int* __restrict__ flags,
    const int* __restrict__ nt, const int* __restrict__ ei, const int* __restrict__ et,
    int* __restrict__ nt32, int* __restrict__ ei32, int* __restrict__ et32)
{
  int i = blockIdx.x*256 + threadIdx.x;
  if (i >= 1000000) return;
  int w = flags[1] ? 2 : 1;
  if (i < 40000)        nt32[i] = nt[(long)i*w];
  else if (i < 680000)  { int j=i-40000;  ei32[j] = ei[(long)j*w]; }
  else                  { int j=i-680000; et32[j] = et[(long)j*w]; }
}

// ---- node-type permutation (64-aligned groups, -1 padding) ----
__global__ __launch_bounds__(256) void pinit_kernel(int* __restrict__ perm, int* __restrict__ pc){
  int i = blockIdx.x*256 + threadIdx.x;
  if (i < 40192) perm[i] = -1;
  if (i < 12) pc[i] = 0;
}
__global__ __launch_bounds__(256) void pcount_kernel(const int* __restrict__ nt, int* __restrict__ pc){
  int i = blockIdx.x*256 + threadIdx.x;
  if (i < N_) atomicAdd(&pc[nt[i]], 1);
}
__global__ void pofs_kernel(int* __restrict__ pc){
  if (threadIdx.x==0 && blockIdx.x==0) {
    pc[8] = 0;
    pc[9] = (pc[0]+63)&~63;
    pc[10] = pc[9] + ((pc[1]+63)&~63);
  }
}
__global__ __launch_bounds__(256) void pscat_kernel(const int* __restrict__ nt,
    int* __restrict__ pc, int* __restrict__ perm){
  int i = blockIdx.x*256 + threadIdx.x;
  if (i >= N_) return;
  int t = nt[i];
  int pos = pc[8+t] + atomicAdd(&pc[4+t], 1);
  perm[pos] = i;
}

// ---- edge-type permutation over first N edges (64-aligned groups, -1 pad) ----
__global__ __launch_bounds__(256) void einit_kernel(int* __restrict__ nperm, int* __restrict__ pc2){
  int i = blockIdx.x*256 + threadIdx.x;
  if (i < 40320) nperm[i] = -1;
  if (i < 16) pc2[i] = 0;
}
__global__ __launch_bounds__(256) void ecount_kernel(const int* __restrict__ et, int* __restrict__ pc2){
  int i = blockIdx.x*256 + threadIdx.x;
  if (i < N_) atomicAdd(&pc2[et[i]], 1);
}
__global__ void eofs_kernel(int* __restrict__ pc2){
  if (threadIdx.x==0 && blockIdx.x==0) {
    pc2[10] = 0;
    #pragma unroll
    for (int r=1;r<R_;++r) pc2[10+r] = pc2[10+r-1] + ((pc2[r-1]+63)&~63);
  }
}
__global__ __launch_bounds__(256) void escat_kernel(const int* __restrict__ et,
    int* __restrict__ pc2, int* __restrict__ nperm){
  int i = blockIdx.x*256 + threadIdx.x;
  if (i >= N_) return;
  int r = et[i];
  int pos = pc2[10+r] + atomicAdd(&pc2[5+r], 1);
  nperm[pos] = i;
}

__global__ __launch_bounds__(256) void init_kernel(
    unsigned* __restrict__ mxkey, float* __restrict__ sumex, int* __restrict__ deg)
{
  int i = blockIdx.x*256 + threadIdx.x;   // 625*256 = N*H
  mxkey[i] = fmono(-1e30f);
  sumex[i] = 0.f;
  if (i < N_) deg[i] = 0;
}

// prepA: raT[r][h][m][d] = rel_att[r][h][d][m]
__global__ __launch_bounds__(256) void prepA_kernel(
    const float* __restrict__ wcf, float* __restrict__ raT)
{
  int i = blockIdx.x*256 + threadIdx.x;
  if (i >= 20480) return;
  int d = i & 31, m = (i>>5) & 31, rh = i >> 10;
  raT[i] = wcf[W_RATT + (rh*32 + d)*32 + m];
}

// prepB: MT[k][i*128+col] = sum_j Wak_k[col,j]*Wkl[i,j];  ck[k][col] = sum_j Wak_k[col,j]*bkl[j]
__global__ __launch_bounds__(128) void prepB_kernel(
    const float* __restrict__ wcf, float* __restrict__ MT, float* __restrict__ ck)
{
  int col = threadIdx.x, i = blockIdx.x, k = blockIdx.y;
  const float* wak = wcf + W_WAK + k*16384 + col*128;
  const float* wkl = wcf + W_WKL + i*128;
  float acc = 0.f, accC = 0.f;
  #pragma unroll 8
  for (int j=0;j<128;++j) {
    float a = wak[j];
    acc  += a * wkl[j];
    if (i==0) accC += a * wcf[W_BKL + j];
  }
  MT[k*16384 + i*128 + col] = acc;
  if (i==0) ck[k*128 + col] = accC;
}

// ---------------------------------------------------------------------------
// gemmt: LDS-tiled f32 GEMM [64 rows x 128 cols], K=128 in 4 chunks.
// powmode: A staged as satt[n,kc]*vp^(y+1) (y=2 cube-rooted); dotmode: sigmoid-dot epilogue.
struct P3 { const float* a[3]; };
__global__ __launch_bounds__(256) void gemmt_kernel(
    P3 xs, const int* __restrict__ flags, int xmode,
    const float* __restrict__ Wbase, int ybstride,
    const float* __restrict__ bias, int ybias,
    const int* __restrict__ perm, const int* __restrict__ nt,
    int dotmode, const float* __restrict__ qlin, const float* __restrict__ ck,
    int powmode, const float* __restrict__ sattp,
    float* __restrict__ out, long yostride)
{
  __shared__ float As[64*36];     // 64 rows x 32 k, stride 36 (pad)
  __shared__ float Ws[4096];      // 32 k x 128 cols, linear
  __shared__ int ridx[64];
  __shared__ int tblk_s;
  int tid = threadIdx.x;
  int y = blockIdx.y;
  int row0 = blockIdx.x*64;
  if (tid < 64) {
    int rr = row0 + tid;
    int rg = perm ? perm[rr] : (rr < N_ ? rr : -1);
    ridx[tid] = rg;
    if (tid==0) tblk_s = (perm && nt && rg>=0) ? nt[rg] : 0;
  }
  __syncthreads();
  if (ridx[0] < 0) return;        // fully padded block (uniform)
  int tblk = tblk_s;
  const float* Wg = Wbase + (long)y*ybstride + (long)tblk*16384;
  const void* X = (const void*)xs.a[y];
  int xf = xmode ? 1 : flags[0];

  int rg_ = tid >> 5;             // 8 row-groups of 8 rows
  int cg  = tid & 31;             // 32 col-groups of 4 cols
  float acc[8][4];
  #pragma unroll
  for (int r=0;r<8;++r){ acc[r][0]=0.f; acc[r][1]=0.f; acc[r][2]=0.f; acc[r][3]=0.f; }

  int sar = tid >> 2;             // staging: row 0..63
  int sks = (tid & 3) * 8;        // staging: k offset 0/8/16/24
  int srow = ridx[sar];

  for (int kc=0;kc<4;++kc) {
    __syncthreads();
    // stage A (64x32)
    {
      float* dst = &As[sar*36 + sks];
      if (srow < 0) {
        #pragma unroll
        for (int j=0;j<8;++j) dst[j]=0.f;
      } else if (powmode) {
        const float4* s4 = reinterpret_cast<const float4*>((const float*)X + (long)srow*128 + kc*32 + sks);
        float4 v0 = s4[0], v1 = s4[1];
        float sc = sattp[srow*4 + kc];           // h == kc
        float tv[8] = {v0.x,v0.y,v0.z,v0.w,v1.x,v1.y,v1.z,v1.w};
        #pragma unroll
        for (int j=0;j<8;++j) {
          float v = tv[j]; float a;
          if (y==0)      a = v*sc;
          else if (y==1) a = v*v*sc;
          else { float a3 = v*v*v*sc;
                 a = (a3==0.f) ? 0.f : copysignf(cbrtf(fabsf(a3)+1e-18f), a3); }
          dst[j] = a;
        }
      } else if (xf) {
        const float4* s4 = reinterpret_cast<const float4*>((const float*)X + (long)srow*128 + kc*32 + sks);
        float4 v0 = s4[0], v1 = s4[1];
        *reinterpret_cast<float4*>(dst)   = v0;
        *reinterpret_cast<float4*>(dst+4) = v1;
      } else {
        const u16* s = (const u16*)X + (long)srow*128 + kc*32 + sks;
        #pragma unroll
        for (int j=0;j<8;++j) dst[j] = bf2f(s[j]);
      }
    }
    // stage W (contiguous 4096 f32 chunk)
    #pragma unroll
    for (int j=0;j<4;++j) {
      float4 v = *reinterpret_cast<const float4*>(Wg + kc*4096 + j*1024 + tid*4);
      *reinterpret_cast<float4*>(&Ws[j*1024 + tid*4]) = v;
    }
    __syncthreads();
    // compute: 8 quads of 4 k
    #pragma unroll
    for (int kq=0;kq<8;++kq) {
      float wv[4][4];
      #pragma unroll
      for (int i=0;i<4;++i) {
        float4 wt = *reinterpret_cast<const float4*>(&Ws[(kq*4+i)*128 + cg*4]);
        wv[i][0]=wt.x; wv[i][1]=wt.y; wv[i][2]=wt.z; wv[i][3]=wt.w;
      }
      #pragma unroll
      for (int r=0;r<8;++r) {
        float4 a4 = *reinterpret_cast<const float4*>(&As[(rg_*8+r)*36 + kq*4]);
        float av[4] = {a4.x, a4.y, a4.z, a4.w};
        #pragma unroll
        for (int i=0;i<4;++i) {
          acc[r][0] += av[i]*wv[i][0];
          acc[r][1] += av[i]*wv[i][1];
          acc[r][2] += av[i]*wv[i][2];
          acc[r][3] += av[i]*wv[i][3];
        }
      }
    }
  }

  if (!dotmode) {
    const float* bp = bias ? (bias + (long)y*ybias + tblk*128 + cg*4) : nullptr;
    float b0=0,b1=0,b2=0,b3=0;
    if (bp){ b0=bp[0]; b1=bp[1]; b2=bp[2]; b3=bp[3]; }
    #pragma unroll
    for (int r=0;r<8;++r) {
      int rowg = ridx[rg_*8+r];
      if (rowg < 0) continue;
      float4 o;
      o.x=acc[r][0]+b0; o.y=acc[r][1]+b1; o.z=acc[r][2]+b2; o.w=acc[r][3]+b3;
      *reinterpret_cast<float4*>(out + (long)y*yostride + (long)rowg*128 + cg*4) = o;
    }
  } else {
    const float* ckp = ck + y*128 + cg*4;
    float c0=ckp[0], c1=ckp[1], c2=ckp[2], c3=ckp[3];
    #pragma unroll
    for (int r=0;r<8;++r) {
      int rowg = ridx[rg_*8+r];
      float d = 0.f;
      if (rowg >= 0) {
        const float* qp = qlin + (long)rowg*128 + cg*4;
        d = (acc[r][0]+c0)*qp[0] + (acc[r][1]+c1)*qp[1]
          + (acc[r][2]+c2)*qp[2] + (acc[r][3]+c3)*qp[3];
      }
      #pragma unroll
      for (int m=16;m;m>>=1) d += __shfl_xor(d, m, 64);
      if (cg==0 && rowg>=0) out[(long)rowg*4 + y] = 1.f/(1.f+expf(-d));
    }
  }
}

// ---------------------------------------------------------------------------
// gemmbd: block-diagonal (4 heads x 32x32) GEMM, 64 rows x 128 cols per block.
// W layout [h][m][c] at h*1024+m*32+c. Optional row perm (-1 pad), row gather,
// per-block W select via et. out[pe, h*32+c] = sum_m X[arow, h*32+m]*W[h][m][c].
__global__ __launch_bounds__(256) void gemmbd_kernel(
    const float* __restrict__ X,
    const float* __restrict__ Wtab, int wsel,
    const int* __restrict__ perm, const int* __restrict__ gsrc, const int* __restrict__ et,
    float* __restrict__ out)
{
  __shared__ float As[64*152];    // [row][h*36 + m], bank-staggered
  __shared__ float Ws[4096];
  __shared__ int ridx[64];
  __shared__ int rsel_s;
  int tid = threadIdx.x;
  int row0 = blockIdx.x*64;
  if (tid < 64) {
    int rr = row0 + tid;
    int pe = perm ? perm[rr] : (rr < N_ ? rr : -1);
    ridx[tid] = pe;
    if (tid == 0) rsel_s = (wsel && pe >= 0) ? et[pe] : 0;
  }
  __syncthreads();
  if (ridx[0] < 0) return;
  const float* Wg = Wtab + (long)(wsel ? rsel_s : 0)*4096;
  // stage W: 16 floats/thread
  #pragma unroll
  for (int j=0;j<4;++j)
    *reinterpret_cast<float4*>(&Ws[j*1024 + tid*4]) =
      *reinterpret_cast<const float4*>(Wg + j*1024 + tid*4);
  // stage A: thread -> row tid>>2, head tid&3 (32 consecutive floats)
  {
    int sar = tid >> 2, sh = tid & 3;
    int pe_s = ridx[sar];
    int arow = (pe_s < 0) ? -1 : (gsrc ? gsrc[pe_s] : pe_s);
    float* dst = &As[sar*152 + sh*36];
    if (arow < 0) {
      #pragma unroll
      for (int j=0;j<8;++j) *reinterpret_cast<float4*>(dst + j*4) = float4{0.f,0.f,0.f,0.f};
    } else {
      const float4* s4 = reinterpret_cast<const float4*>(X + (long)arow*128 + sh*32);
      #pragma unroll
      for (int j=0;j<8;++j) *reinterpret_cast<float4*>(dst + j*4) = s4[j];
    }
  }
  __syncthreads();
  int rg_ = tid >> 5, cg = tid & 31;
  int h = cg >> 3, c4 = (cg & 7)*4;
  float acc[8][4];
  #pragma unroll
  for (int r=0;r<8;++r){ acc[r][0]=0.f; acc[r][1]=0.f; acc[r][2]=0.f; acc[r][3]=0.f; }
  #pragma unroll
  for (int mq=0;mq<8;++mq) {
    float wv[4][4];
    #pragma unroll
    for (int i=0;i<4;++i) {
      float4 wt = *reinterpret_cast<const float4*>(&Ws[h*1024 + (mq*4+i)*32 + c4]);
      wv[i][0]=wt.x; wv[i][1]=wt.y; wv[i][2]=wt.z; wv[i][3]=wt.w;
    }
    #pragma unroll
    for (int r=0;r<8;++r) {
      float4 a4 = *reinterpret_cast<const float4*>(&As[(rg_*8+r)*152 + h*36 + mq*4]);
      float av[4] = {a4.x,a4.y,a4.z,a4.w};
      #pragma unroll
      for (int i=0;i<4;++i) {
        acc[r][0]+=av[i]*wv[i][0]; acc[r][1]+=av[i]*wv[i][1];
        acc[r][2]+=av[i]*wv[i][2]; acc[r][3]+=av[i]*wv[i][3];
      }
    }
  }
  #pragma unroll
  for (int r=0;r<8;++r) {
    int pe = ridx[rg_*8+r];
    if (pe < 0) continue;
    float4 o = {acc[r][0],acc[r][1],acc[r][2],acc[r][3]};
    *reinterpret_cast<float4*>(out + (long)pe*128 + h*32 + c4) = o;
  }
}

// ---------------------------------------------------------------------------
// per-relation edge pass: logit = dot32(kn[src,h], qtr[tgt,h]) * pri / sqrt(32)
__global__ __launch_bounds__(256) void epass_kernel(
    const float* __restrict__ kn, const float* __restrict__ qtr, const float* __restrict__ wcf,
    const int* __restrict__ ei, const int* __restrict__ et, int rsel,
    float* __restrict__ logits, unsigned* __restrict__ mxkey, int* __restrict__ deg)
{
  int gid = blockIdx.x*256 + threadIdx.x;   // E*H
  int e = gid >> 2, h = gid & 3;
  if (et[e] != rsel) return;
  int s = ei[e], t = ei[E_+e];
  const float4* ka = reinterpret_cast<const float4*>(kn + (long)s*128 + h*32);
  const float4* qa = reinterpret_cast<const float4*>(qtr + (long)t*128 + h*32);
  float acc = 0.f;
  #pragma unroll
  for (int i=0;i<8;++i) {
    float4 a = ka[i], b = qa[i];
    acc += a.x*b.x + a.y*b.y + a.z*b.z + a.w*b.w;
  }
  float lg = acc * wcf[W_PRI + rsel*H_+h] * 0.17677669529663687f;
  logits[gid] = lg;
  atomicMax(mxkey + t*H_+h, fmono(lg));
  if (h==0) atomicAdd(deg + t, 1);
}

__global__ __launch_bounds__(256) void eexp_kernel(
    const int* __restrict__ ei, float* __restrict__ logits,
    const unsigned* __restrict__ mxkey, float* __restrict__ sumex)
{
  int gid = blockIdx.x*256 + threadIdx.x;
  int e = gid >> 2, h = gid & 3;
  int t = ei[E_+e];
  float d = fminf(logits[gid] - monof(mxkey[t*H_+h]), 0.f);
  float ex = expf(d);
  logits[gid] = ex;
  atomicAdd(sumex + t*H_+h, ex);
}

// satt[n*4+h] = deg[n] * ex[n*4+h] / (sumex[tgt[n]*4+h] + 1e-16)
__global__ __launch_bounds__(256) void satt_kernel(
    const int* __restrict__ ei, const float* __restrict__ ex, const float* __restrict__ sumex,
    const int* __restrict__ deg, float* __restrict__ satt)
{
  int i = blockIdx.x*256 + threadIdx.x;   // N*H
  int n = i >> 2, h = i & 3;
  int t = ei[E_+n];
  satt[i] = (float)deg[n] * ex[i] / (sumex[t*H_+h] + 1e-16f);
}

// gatemix: res = sum_k t_k·ag_k; h = gelu_exact(res)
__global__ __launch_bounds__(256) void gatemix_kernel(
    const float* __restrict__ tval,
    const float* __restrict__ ag0, const float* __restrict__ ag1, const float* __restrict__ ag2,
    float* __restrict__ hout)
{
  long gid = (long)blockIdx.x*256 + threadIdx.x;   // N*128
  int n = (int)(gid >> 7);
  float res = tval[n*4+0]*ag0[gid] + tval[n*4+1]*ag1[gid] + tval[n*4+2]*ag2[gid];
  hout[gid] = 0.5f*res*(1.f+erff(res*0.70710678118654752f));
}

__global__ __launch_bounds__(256) void lnf_kernel(
    const float* __restrict__ trans, const void* __restrict__ x, const int* __restrict__ flags,
    const int* __restrict__ nt, const float* __restrict__ wcf, void* __restrict__ outv)
{
  int wave = threadIdx.x >> 6, lane = threadIdx.x & 63;
  int n = blockIdx.x*4 + wave;
  int j = lane*2;
  int xf = flags[0];
  int t = nt[n];
  float alpha = 1.f/(1.f+expf(-wcf[W_SKIP+t]));
  long base = (long)n*128 + j;
  float y0 = alpha*trans[base]   + (1.f-alpha)*ldx(x, base,   xf);
  float y1 = alpha*trans[base+1] + (1.f-alpha)*ldx(x, base+1, xf);
  float mu = wredsum(y0+y1) * (1.f/128.f);
  float d0 = y0-mu, d1 = y1-mu;
  float var = wredsum(d0*d0+d1*d1) * (1.f/128.f);
  float inv = rsqrtf(var + 1e-5f);
  float o0 = d0*inv*wcf[W_LNG + t*128+j]   + wcf[W_LNB + t*128+j];
  float o1 = d1*inv*wcf[W_LNG + t*128+j+1] + wcf[W_LNB + t*128+j+1];
  if (xf) {
    ((float*)outv)[base]   = o0;
    ((float*)outv)[base+1] = o1;
  } else {
    unsigned o = (unsigned)f2bf(o0) | ((unsigned)f2bf(o1)<<16);
    *reinterpret_cast<unsigned*>(((u16*)outv)+base) = o;
  }
}

// ---------------------------------------------------------------------------
extern "C" void kernel_launch(void* const* d_in, const int* in_sizes, int n_in,
                              void* d_out, int out_size, void* d_ws, size_t ws_size,
                              hipStream_t stream) {
  char* w = (char*)d_ws;
  int*      flags = (int*)     (w + OFF_FLAGS);
  float*    wcf   = (float*)   (w + OFF_WCF);
  int*      nt32  = (int*)     (w + OFF_NT32);
  int*      ei32  = (int*)     (w + OFF_EI32);
  int*      et32  = (int*)     (w + OFF_ET32);
  int*      perm  = (int*)     (w + OFF_PERM);
  int*      pcnt  = (int*)     (w + OFF_PCNT);
  int*      pc2   = (int*)     (w + OFF_PCNT + 128);
  float*    raT   = (float*)   (w + OFF_TVAL);   // raT -> satt -> tval (disjoint)
  float*    satt  = (float*)   (w + OFF_TVAL);
  float*    tval  = (float*)   (w + OFF_TVAL);
  int*      nperm = (int*)     (w + OFF_NPERM);
  float*    logits= (float*)   (w + OFF_LOG);
  unsigned* mxkey = (unsigned*)(w + OFF_LOG + 5120000);
  float*    sumex = (float*)   (w + OFF_LOG + 5760000);
  int*      deg   = (int*)     (w + OFF_LOG + 6400000);
  float*    MT    = (float*)   (w + OFF_LOG);            // overlays dead softmax scratch
  float*    ckb   = (float*)   (w + OFF_LOG + 786432);
  float*    qn    = (float*)   (w + OFF_QN);
  float*    ag0   = (float*)   (w + OFF_QN);
  float*    trans = (float*)   (w + OFF_QN);
  float*    kn    = (float*)   (w + OFF_KN);
  float*    ag1   = (float*)   (w + OFF_KN);
  float*    vn    = (float*)   (w + OFF_VN);
  float*    ag2   = (float*)   (w + OFF_VN);
  float*    qlin  = (float*)   (w + OFF_QLIN);
  float*    hbuf  = (float*)   (w + OFF_QLIN);
  float*    qtrb  = (float*)   (w + OFF_QTR);
  float*    vp    = (float*)   (w + OFF_QTR);

  // s0: dtype detect + canonicalize
  detect_kernel<<<1,256,0,stream>>>((const u16*)d_in[0], (const int*)d_in[1], flags);
  FPtrs fp;
  fp.p[0]=d_in[5];  fp.p[1]=d_in[7];  fp.p[2]=d_in[9];  fp.p[3]=d_in[11];
  fp.p[4]=d_in[6];  fp.p[5]=d_in[8];  fp.p[6]=d_in[10]; fp.p[7]=d_in[12];
  fp.p[8]=d_in[13]; fp.p[9]=d_in[14]; fp.p[10]=d_in[15];fp.p[11]=d_in[16];
  fp.p[12]=d_in[17];fp.p[13]=d_in[18];fp.p[14]=d_in[19];fp.p[15]=d_in[20];
  fp.p[16]=d_in[21];fp.p[17]=d_in[22];fp.p[18]=d_in[23];fp.p[19]=d_in[24];
  convf_kernel<<<1451,256,0,stream>>>(flags, fp, wcf);
  idxconv_kernel<<<3907,256,0,stream>>>(flags, (const int*)d_in[1],
                                        (const int*)d_in[2], (const int*)d_in[3],
                                        nt32, ei32, et32);
  // s0.7: node-type perm
  pinit_kernel <<<157,256,0,stream>>>(perm, pcnt);
  pcount_kernel<<<157,256,0,stream>>>(nt32, pcnt);
  pofs_kernel  <<<1,64,0,stream>>>(pcnt);
  pscat_kernel <<<157,256,0,stream>>>(nt32, pcnt, perm);
  // s0.8: edge-type perm over first N edges
  einit_kernel <<<158,256,0,stream>>>(nperm, pc2);
  ecount_kernel<<<157,256,0,stream>>>(et32, pc2);
  eofs_kernel  <<<1,64,0,stream>>>(pc2);
  escat_kernel <<<157,256,0,stream>>>(et32, pc2, nperm);
  // s1: raT
  prepA_kernel<<<80,256,0,stream>>>(wcf, raT);

  // s2: q/k/v typed projections (one batched dispatch)
  P3 xin; xin.a[0]=(const float*)d_in[0]; xin.a[1]=xin.a[0]; xin.a[2]=xin.a[0];
  gemmt_kernel<<<dim3(628,3),256,0,stream>>>(xin, flags, 0,
      wcf+W_QW, 49152, wcf+W_QB, 384, perm, nt32, 0, nullptr, nullptr, 0, nullptr,
      qn, 5120000);
  // s3: qlin
  gemmt_kernel<<<dim3(625,1),256,0,stream>>>(xin, flags, 0,
      wcf+W_WQ, 0, wcf+W_BQ, 0, nullptr, nullptr, 0, nullptr, nullptr, 0, nullptr,
      qlin, 0);

  // s5.5: init softmax accumulators
  init_kernel<<<625,256,0,stream>>>(mxkey, sumex, deg);

  // s6: per-relation qtr (gemmbd) + edge pass
  for (int r=0; r<R_; ++r) {
    gemmbd_kernel<<<625,256,0,stream>>>(qn, raT + r*4096, 0, nullptr, nullptr, nullptr, qtrb);
    epass_kernel<<<5000,256,0,stream>>>(kn, qtrb, wcf, ei32, et32, r, logits, mxkey, deg);
  }
  // s7: exp + segment-sum
  eexp_kernel<<<5000,256,0,stream>>>(ei32, logits, mxkey, sumex);

  // s7.5: vp[n] = vn[src[n]] @ BD(rel_msg[et[n]])  (edge-type-sorted blocks)
  gemmbd_kernel<<<630,256,0,stream>>>(vn, wcf+W_RMSG, 1, nperm, ei32, et32, vp);

  // s7.75: satt = deg·ex/sumex  (softmax scratch dead after this)
  satt_kernel<<<625,256,0,stream>>>(ei32, logits, sumex, deg, satt);

  // s8.25: MT/ck into dead softmax region
  prepB_kernel<<<dim3(128,3),128,0,stream>>>(wcf, MT, ckb);

  // s8.5: ag_k = pow_k(vp)·satt @ WMk[k]  (powmode gemmt, batched k)
  P3 xvp; xvp.a[0]=vp; xvp.a[1]=vp; xvp.a[2]=vp;
  gemmt_kernel<<<dim3(625,3),256,0,stream>>>(xvp, flags, 1,
      wcf+W_WMK, 16384, nullptr, 0, nullptr, nullptr, 0, nullptr, nullptr, 1, satt,
      ag0, 5120000);

  // s9: gate scalars (dot-mode gemmt)
  P3 xag; xag.a[0]=ag0; xag.a[1]=ag1; xag.a[2]=ag2;
  gemmt_kernel<<<dim3(625,3),256,0,stream>>>(xag, flags, 1,
      MT, 16384, nullptr, 0, nullptr, nullptr, 1, qlin, ckb, 0, nullptr,
      tval, 0);

  // s10: mix + gelu -> hbuf (overlays qlin)
  gatemix_kernel<<<20000,256,0,stream>>>(tval, ag0, ag1, ag2, hbuf);

  // s11: trans = typed(h, a_w, a_b)
  P3 xh; xh.a[0]=hbuf; xh.a[1]=hbuf; xh.a[2]=hbuf;
  gemmt_kernel<<<dim3(628,1),256,0,stream>>>(xh, flags, 1,
      wcf+W_AW, 0, wcf+W_AB, 0, perm, nt32, 0, nullptr, nullptr, 0, nullptr,
      trans, 0);

  // s12: skip-mix + per-type LayerNorm -> out
  lnf_kernel<<<10000,256,0,stream>>>(trans, d_in[0], flags, nt32, wcf, d_out);

  (void)in_sizes; (void)n_in; (void)out_size; (void)ws_size;
}

// Round 8
// 658.442 us; speedup vs baseline: 2.4311x; 2.4311x over previous
//
#include <hip/hip_runtime.h>

// GeneralConv_30820685316781 — f32 build, round 8: LDS-histogram sorts (kill atomic contention)
#define N_ 40000
#define E_ 320000
#define D_ 128
#define H_ 4
#define T_ 3
#define R_ 5

typedef unsigned short u16;

__device__ __forceinline__ float bf2f(u16 h){ return __uint_as_float(((unsigned)h)<<16); }
__device__ __forceinline__ u16 f2bf(float f){
  unsigned u = __float_as_uint(f);
  u += 0x7fffu + ((u>>16)&1u);     // RNE
  return (u16)(u>>16);
}
__device__ __forceinline__ unsigned fmono(float f){
  unsigned u = __float_as_uint(f);
  return (u>>31) ? ~u : (u | 0x80000000u);
}
__device__ __forceinline__ float monof(unsigned u){
  return (u>>31) ? __uint_as_float(u & 0x7fffffffu) : __uint_as_float(~u);
}
__device__ __forceinline__ float ldx(const void* p, long i, int f32){
  return f32 ? ((const float*)p)[i] : bf2f(((const u16*)p)[i]);
}
__device__ __forceinline__ float wredsum(float v){
  #pragma unroll
  for (int m=32;m;m>>=1) v += __shfl_xor(v, m, 64);
  return v;
}

// wcf element offsets (f32 canonical weight buffer)
#define W_QW 0
#define W_KW 49152
#define W_VW 98304
#define W_AW 147456
#define W_QB 196608
#define W_KB 196992
#define W_VB 197376
#define W_AB 197760
#define W_PRI 198144
#define W_RATT 198164
#define W_RMSG 218644
#define W_WMK 239124
#define W_WAK 288276
#define W_WQ 337428
#define W_BQ 353812
#define W_WKL 353940
#define W_BKL 370324
#define W_SKIP 370452
#define W_LNG 370455
#define W_LNB 370839
#define W_TOT 371223

// ---- workspace layout (bytes). Peak 115,248,640 (= round-6/7 proven). ----
#define OFF_FLAGS 0ul
#define OFF_WCF   512ul
#define OFF_NT32  1485824ul
#define OFF_EI32  1646080ul
#define OFF_ET32  4206592ul
#define OFF_PERM  5486592ul    // node perm: 40192 ints, 64-aligned type groups, -1 pad
#define OFF_PCNT  5647360ul    // pcnt[12] | pc2[16] at +128
#define OFF_TVAL  5647872ul    // raT (80KB, s1-s6) ; satt (s7.75-s8) ; tval (s9-s10)
#define OFF_NPERM 5737984ul    // 40320 ints (edge-type-sorted first-N edges)
#define OFF_LOG   6288384ul    // logits 5.12M | mxkey .64M | sumex .64M | deg .16M ; MT+ck overlay after satt
#define OFF_QN    12848640ul   // qn -> ag0 -> trans
#define OFF_KN    33328640ul   // kn -> ag1
#define OFF_VN    53808640ul   // vn -> ag2
#define OFF_QLIN  74288640ul   // qlin -> hbuf
#define OFF_QTR   94768640ul   // qtrb (s6) -> vp (s7.5-s8)

// ---------------------------------------------------------------------------
__global__ __launch_bounds__(256) void detect_kernel(
    const u16* __restrict__ xs, const int* __restrict__ nt, int* __restrict__ flags)
{
  __shared__ int sBig, sZero, sNz;
  int tid = threadIdx.x;
  if (tid==0){ sBig=0; sZero=0; sNz=0; }
  __syncthreads();
  int big=0, zc=0;
  for (int i=tid; i<1024; i+=256) {
    u16 v = xs[2*i];
    int e = (v>>7)&0xFF;
    big += (e >= 200);
    zc  += (v == 0);
  }
  int nz=0;
  for (int i=tid; i<1024; i+=256) nz += (nt[2*i+1] != 0);
  atomicAdd(&sBig, big); atomicAdd(&sZero, zc); atomicAdd(&sNz, nz);
  __syncthreads();
  if (tid==0) {
    flags[0] = (sBig > 64) || (sZero > 900);
    flags[1] = (sNz == 0);
  }
}

struct FPtrs { const void* p[20]; };
__global__ __launch_bounds__(256) void convf_kernel(
    const int* __restrict__ flags, FPtrs ptrs, float* __restrict__ wcf)
{
  const int start[21] = {0,49152,98304,147456,196608,196992,197376,197760,198144,
    198164,218644,239124,288276,337428,353812,353940,370324,370452,370455,370839,371223};
  int i = blockIdx.x*256 + threadIdx.x;
  if (i >= W_TOT) return;
  int arr = 0;
  #pragma unroll
  for (int a=1; a<20; ++a) arr += (i >= start[a]);
  int local = i - start[arr];
  wcf[i] = ldx(ptrs.p[arr], local, flags[0]);
}

__global__ __launch_bounds__(256) void idxconv_kernel(
    const int* __restrict__ flags,
    const int* __restrict__ nt, const int* __restrict__ ei, const int* __restrict__ et,
    int* __restrict__ nt32, int* __restrict__ ei32, int* __restrict__ et32)
{
  int i = blockIdx.x*256 + threadIdx.x;
  if (i >= 1000000) return;
  int w = flags[1] ? 2 : 1;
  if (i < 40000)        nt32[i] = nt[(long)i*w];
  else if (i < 680000)  { int j=i-40000;  ei32[j] = ei[(long)j*w]; }
  else                  { int j=i-680000; et32[j] = et[(long)j*w]; }
}

// ---- low-contention counting sort (generic, ntypes<=8) ----
__global__ __launch_bounds__(256) void pinit_kernel(int* __restrict__ perm, int* __restrict__ pc){
  int i = blockIdx.x*256 + threadIdx.x;
  if (i < 40192) perm[i] = -1;
  if (i < 12) pc[i] = 0;
}
__global__ __launch_bounds__(256) void einit_kernel(int* __restrict__ nperm, int* __restrict__ pc2){
  int i = blockIdx.x*256 + threadIdx.x;
  if (i < 40320) nperm[i] = -1;
  if (i < 16) pc2[i] = 0;
}
// per-block LDS histogram -> ntypes global atomics per block
__global__ __launch_bounds__(256) void cnt_kernel(
    const int* __restrict__ keys, int n, int ntypes, int* __restrict__ gcnt)
{
  __shared__ int lh[8];
  if (threadIdx.x < ntypes) lh[threadIdx.x] = 0;
  __syncthreads();
  int i = blockIdx.x*256 + threadIdx.x;
  if (i < n) atomicAdd(&lh[keys[i]], 1);
  __syncthreads();
  if (threadIdx.x < ntypes && lh[threadIdx.x])
    atomicAdd(&gcnt[threadIdx.x], lh[threadIdx.x]);
}
__global__ void pofs_kernel(int* __restrict__ pc){
  if (threadIdx.x==0 && blockIdx.x==0) {
    pc[8] = 0;
    pc[9] = (pc[0]+63)&~63;
    pc[10] = pc[9] + ((pc[1]+63)&~63);
  }
}
__global__ void eofs_kernel(int* __restrict__ pc2){
  if (threadIdx.x==0 && blockIdx.x==0) {
    pc2[10] = 0;
    #pragma unroll
    for (int r=1;r<R_;++r) pc2[10+r] = pc2[10+r-1] + ((pc2[r-1]+63)&~63);
  }
}
// per-block LDS ranks + one global reservation atomic per type per block
__global__ __launch_bounds__(256) void scat_kernel(
    const int* __restrict__ keys, int n, int ntypes,
    const int* __restrict__ ofs, int* __restrict__ fill, int* __restrict__ perm)
{
  __shared__ int lh[8];
  __shared__ int lbase[8];
  if (threadIdx.x < ntypes) lh[threadIdx.x] = 0;
  __syncthreads();
  int i = blockIdx.x*256 + threadIdx.x;
  int t = 0, rank = 0;
  bool ok = (i < n);
  if (ok) { t = keys[i]; rank = atomicAdd(&lh[t], 1); }
  __syncthreads();
  if (threadIdx.x < ntypes)
    lbase[threadIdx.x] = lh[threadIdx.x] ? atomicAdd(&fill[threadIdx.x], lh[threadIdx.x]) : 0;
  __syncthreads();
  if (ok) perm[ofs[t] + lbase[t] + rank] = i;
}

__global__ __launch_bounds__(256) void init_kernel(
    unsigned* __restrict__ mxkey, float* __restrict__ sumex, int* __restrict__ deg)
{
  int i = blockIdx.x*256 + threadIdx.x;   // 625*256 = N*H
  mxkey[i] = fmono(-1e30f);
  sumex[i] = 0.f;
  if (i < N_) deg[i] = 0;
}

// prepA: raT[r][h][m][d] = rel_att[r][h][d][m]
__global__ __launch_bounds__(256) void prepA_kernel(
    const float* __restrict__ wcf, float* __restrict__ raT)
{
  int i = blockIdx.x*256 + threadIdx.x;
  if (i >= 20480) return;
  int d = i & 31, m = (i>>5) & 31, rh = i >> 10;
  raT[i] = wcf[W_RATT + (rh*32 + d)*32 + m];
}

// prepB: MT[k][i*128+col] = sum_j Wak_k[col,j]*Wkl[i,j];  ck[k][col] = sum_j Wak_k[col,j]*bkl[j]
__global__ __launch_bounds__(128) void prepB_kernel(
    const float* __restrict__ wcf, float* __restrict__ MT, float* __restrict__ ck)
{
  int col = threadIdx.x, i = blockIdx.x, k = blockIdx.y;
  const float* wak = wcf + W_WAK + k*16384 + col*128;
  const float* wkl = wcf + W_WKL + i*128;
  float acc = 0.f, accC = 0.f;
  #pragma unroll 8
  for (int j=0;j<128;++j) {
    float a = wak[j];
    acc  += a * wkl[j];
    if (i==0) accC += a * wcf[W_BKL + j];
  }
  MT[k*16384 + i*128 + col] = acc;
  if (i==0) ck[k*128 + col] = accC;
}

// ---------------------------------------------------------------------------
// gemmt: LDS-tiled f32 GEMM [64 rows x 128 cols], K=128 in 4 chunks.
// powmode: A staged as satt[n,kc]*vp^(y+1) (y=2 cube-rooted); dotmode: sigmoid-dot epilogue.
struct P3 { const float* a[3]; };
__global__ __launch_bounds__(256) void gemmt_kernel(
    P3 xs, const int* __restrict__ flags, int xmode,
    const float* __restrict__ Wbase, int ybstride,
    const float* __restrict__ bias, int ybias,
    const int* __restrict__ perm, const int* __restrict__ nt,
    int dotmode, const float* __restrict__ qlin, const float* __restrict__ ck,
    int powmode, const float* __restrict__ sattp,
    float* __restrict__ out, long yostride)
{
  __shared__ float As[64*36];     // 64 rows x 32 k, stride 36 (pad)
  __shared__ float Ws[4096];      // 32 k x 128 cols, linear
  __shared__ int ridx[64];
  __shared__ int tblk_s;
  int tid = threadIdx.x;
  int y = blockIdx.y;
  int row0 = blockIdx.x*64;
  if (tid < 64) {
    int rr = row0 + tid;
    int rg = perm ? perm[rr] : (rr < N_ ? rr : -1);
    ridx[tid] = rg;
    if (tid==0) tblk_s = (perm && nt && rg>=0) ? nt[rg] : 0;
  }
  __syncthreads();
  if (ridx[0] < 0) return;        // fully padded block (uniform)
  int tblk = tblk_s;
  const float* Wg = Wbase + (long)y*ybstride + (long)tblk*16384;
  const void* X = (const void*)xs.a[y];
  int xf = xmode ? 1 : flags[0];

  int rg_ = tid >> 5;             // 8 row-groups of 8 rows
  int cg  = tid & 31;             // 32 col-groups of 4 cols
  float acc[8][4];
  #pragma unroll
  for (int r=0;r<8;++r){ acc[r][0]=0.f; acc[r][1]=0.f; acc[r][2]=0.f; acc[r][3]=0.f; }

  int sar = tid >> 2;             // staging: row 0..63
  int sks = (tid & 3) * 8;        // staging: k offset 0/8/16/24
  int srow = ridx[sar];

  for (int kc=0;kc<4;++kc) {
    __syncthreads();
    // stage A (64x32)
    {
      float* dst = &As[sar*36 + sks];
      if (srow < 0) {
        #pragma unroll
        for (int j=0;j<8;++j) dst[j]=0.f;
      } else if (powmode) {
        const float4* s4 = reinterpret_cast<const float4*>((const float*)X + (long)srow*128 + kc*32 + sks);
        float4 v0 = s4[0], v1 = s4[1];
        float sc = sattp[srow*4 + kc];           // h == kc
        float tv[8] = {v0.x,v0.y,v0.z,v0.w,v1.x,v1.y,v1.z,v1.w};
        #pragma unroll
        for (int j=0;j<8;++j) {
          float v = tv[j]; float a;
          if (y==0)      a = v*sc;
          else if (y==1) a = v*v*sc;
          else { float a3 = v*v*v*sc;
                 a = (a3==0.f) ? 0.f : copysignf(cbrtf(fabsf(a3)+1e-18f), a3); }
          dst[j] = a;
        }
      } else if (xf) {
        const float4* s4 = reinterpret_cast<const float4*>((const float*)X + (long)srow*128 + kc*32 + sks);
        float4 v0 = s4[0], v1 = s4[1];
        *reinterpret_cast<float4*>(dst)   = v0;
        *reinterpret_cast<float4*>(dst+4) = v1;
      } else {
        const u16* s = (const u16*)X + (long)srow*128 + kc*32 + sks;
        #pragma unroll
        for (int j=0;j<8;++j) dst[j] = bf2f(s[j]);
      }
    }
    // stage W (contiguous 4096 f32 chunk)
    #pragma unroll
    for (int j=0;j<4;++j) {
      float4 v = *reinterpret_cast<const float4*>(Wg + kc*4096 + j*1024 + tid*4);
      *reinterpret_cast<float4*>(&Ws[j*1024 + tid*4]) = v;
    }
    __syncthreads();
    // compute: 8 quads of 4 k
    #pragma unroll
    for (int kq=0;kq<8;++kq) {
      float wv[4][4];
      #pragma unroll
      for (int i=0;i<4;++i) {
        float4 wt = *reinterpret_cast<const float4*>(&Ws[(kq*4+i)*128 + cg*4]);
        wv[i][0]=wt.x; wv[i][1]=wt.y; wv[i][2]=wt.z; wv[i][3]=wt.w;
      }
      #pragma unroll
      for (int r=0;r<8;++r) {
        float4 a4 = *reinterpret_cast<const float4*>(&As[(rg_*8+r)*36 + kq*4]);
        float av[4] = {a4.x, a4.y, a4.z, a4.w};
        #pragma unroll
        for (int i=0;i<4;++i) {
          acc[r][0] += av[i]*wv[i][0];
          acc[r][1] += av[i]*wv[i][1];
          acc[r][2] += av[i]*wv[i][2];
          acc[r][3] += av[i]*wv[i][3];
        }
      }
    }
  }

  if (!dotmode) {
    const float* bp = bias ? (bias + (long)y*ybias + tblk*128 + cg*4) : nullptr;
    float b0=0,b1=0,b2=0,b3=0;
    if (bp){ b0=bp[0]; b1=bp[1]; b2=bp[2]; b3=bp[3]; }
    #pragma unroll
    for (int r=0;r<8;++r) {
      int rowg = ridx[rg_*8+r];
      if (rowg < 0) continue;
      float4 o;
      o.x=acc[r][0]+b0; o.y=acc[r][1]+b1; o.z=acc[r][2]+b2; o.w=acc[r][3]+b3;
      *reinterpret_cast<float4*>(out + (long)y*yostride + (long)rowg*128 + cg*4) = o;
    }
  } else {
    const float* ckp = ck + y*128 + cg*4;
    float c0=ckp[0], c1=ckp[1], c2=ckp[2], c3=ckp[3];
    #pragma unroll
    for (int r=0;r<8;++r) {
      int rowg = ridx[rg_*8+r];
      float d = 0.f;
      if (rowg >= 0) {
        const float* qp = qlin + (long)rowg*128 + cg*4;
        d = (acc[r][0]+c0)*qp[0] + (acc[r][1]+c1)*qp[1]
          + (acc[r][2]+c2)*qp[2] + (acc[r][3]+c3)*qp[3];
      }
      #pragma unroll
      for (int m=16;m;m>>=1) d += __shfl_xor(d, m, 64);
      if (cg==0 && rowg>=0) out[(long)rowg*4 + y] = 1.f/(1.f+expf(-d));
    }
  }
}

// ---------------------------------------------------------------------------
// gemmbd: block-diagonal (4 heads x 32x32) GEMM, 64 rows x 128 cols per block.
__global__ __launch_bounds__(256) void gemmbd_kernel(
    const float* __restrict__ X,
    const float* __restrict__ Wtab, int wsel,
    const int* __restrict__ perm, const int* __restrict__ gsrc, const int* __restrict__ et,
    float* __restrict__ out)
{
  __shared__ float As[64*152];    // [row][h*36 + m], bank-staggered
  __shared__ float Ws[4096];
  __shared__ int ridx[64];
  __shared__ int rsel_s;
  int tid = threadIdx.x;
  int row0 = blockIdx.x*64;
  if (tid < 64) {
    int rr = row0 + tid;
    int pe = perm ? perm[rr] : (rr < N_ ? rr : -1);
    ridx[tid] = pe;
    if (tid == 0) rsel_s = (wsel && pe >= 0) ? et[pe] : 0;
  }
  __syncthreads();
  if (ridx[0] < 0) return;
  const float* Wg = Wtab + (long)(wsel ? rsel_s : 0)*4096;
  #pragma unroll
  for (int j=0;j<4;++j)
    *reinterpret_cast<float4*>(&Ws[j*1024 + tid*4]) =
      *reinterpret_cast<const float4*>(Wg + j*1024 + tid*4);
  {
    int sar = tid >> 2, sh = tid & 3;
    int pe_s = ridx[sar];
    int arow = (pe_s < 0) ? -1 : (gsrc ? gsrc[pe_s] : pe_s);
    float* dst = &As[sar*152 + sh*36];
    if (arow < 0) {
      #pragma unroll
      for (int j=0;j<8;++j) *reinterpret_cast<float4*>(dst + j*4) = float4{0.f,0.f,0.f,0.f};
    } else {
      const float4* s4 = reinterpret_cast<const float4*>(X + (long)arow*128 + sh*32);
      #pragma unroll
      for (int j=0;j<8;++j) *reinterpret_cast<float4*>(dst + j*4) = s4[j];
    }
  }
  __syncthreads();
  int rg_ = tid >> 5, cg = tid & 31;
  int h = cg >> 3, c4 = (cg & 7)*4;
  float acc[8][4];
  #pragma unroll
  for (int r=0;r<8;++r){ acc[r][0]=0.f; acc[r][1]=0.f; acc[r][2]=0.f; acc[r][3]=0.f; }
  #pragma unroll
  for (int mq=0;mq<8;++mq) {
    float wv[4][4];
    #pragma unroll
    for (int i=0;i<4;++i) {
      float4 wt = *reinterpret_cast<const float4*>(&Ws[h*1024 + (mq*4+i)*32 + c4]);
      wv[i][0]=wt.x; wv[i][1]=wt.y; wv[i][2]=wt.z; wv[i][3]=wt.w;
    }
    #pragma unroll
    for (int r=0;r<8;++r) {
      float4 a4 = *reinterpret_cast<const float4*>(&As[(rg_*8+r)*152 + h*36 + mq*4]);
      float av[4] = {a4.x,a4.y,a4.z,a4.w};
      #pragma unroll
      for (int i=0;i<4;++i) {
        acc[r][0]+=av[i]*wv[i][0]; acc[r][1]+=av[i]*wv[i][1];
        acc[r][2]+=av[i]*wv[i][2]; acc[r][3]+=av[i]*wv[i][3];
      }
    }
  }
  #pragma unroll
  for (int r=0;r<8;++r) {
    int pe = ridx[rg_*8+r];
    if (pe < 0) continue;
    float4 o = {acc[r][0],acc[r][1],acc[r][2],acc[r][3]};
    *reinterpret_cast<float4*>(out + (long)pe*128 + h*32 + c4) = o;
  }
}

// ---------------------------------------------------------------------------
__global__ __launch_bounds__(256) void epass_kernel(
    const float* __restrict__ kn, const float* __restrict__ qtr, const float* __restrict__ wcf,
    const int* __restrict__ ei, const int* __restrict__ et, int rsel,
    float* __restrict__ logits, unsigned* __restrict__ mxkey, int* __restrict__ deg)
{
  int gid = blockIdx.x*256 + threadIdx.x;   // E*H
  int e = gid >> 2, h = gid & 3;
  if (et[e] != rsel) return;
  int s = ei[e], t = ei[E_+e];
  const float4* ka = reinterpret_cast<const float4*>(kn + (long)s*128 + h*32);
  const float4* qa = reinterpret_cast<const float4*>(qtr + (long)t*128 + h*32);
  float acc = 0.f;
  #pragma unroll
  for (int i=0;i<8;++i) {
    float4 a = ka[i], b = qa[i];
    acc += a.x*b.x + a.y*b.y + a.z*b.z + a.w*b.w;
  }
  float lg = acc * wcf[W_PRI + rsel*H_+h] * 0.17677669529663687f;
  logits[gid] = lg;
  atomicMax(mxkey + t*H_+h, fmono(lg));
  if (h==0) atomicAdd(deg + t, 1);
}

__global__ __launch_bounds__(256) void eexp_kernel(
    const int* __restrict__ ei, float* __restrict__ logits,
    const unsigned* __restrict__ mxkey, float* __restrict__ sumex)
{
  int gid = blockIdx.x*256 + threadIdx.x;
  int e = gid >> 2, h = gid & 3;
  int t = ei[E_+e];
  float d = fminf(logits[gid] - monof(mxkey[t*H_+h]), 0.f);
  float ex = expf(d);
  logits[gid] = ex;
  atomicAdd(sumex + t*H_+h, ex);
}

// satt[n*4+h] = deg[n] * ex[n*4+h] / (sumex[tgt[n]*4+h] + 1e-16)
__global__ __launch_bounds__(256) void satt_kernel(
    const int* __restrict__ ei, const float* __restrict__ ex, const float* __restrict__ sumex,
    const int* __restrict__ deg, float* __restrict__ satt)
{
  int i = blockIdx.x*256 + threadIdx.x;   // N*H
  int n = i >> 2, h = i & 3;
  int t = ei[E_+n];
  satt[i] = (float)deg[n] * ex[i] / (sumex[t*H_+h] + 1e-16f);
}

// gatemix: res = sum_k t_k·ag_k; h = gelu_exact(res)
__global__ __launch_bounds__(256) void gatemix_kernel(
    const float* __restrict__ tval,
    const float* __restrict__ ag0, const float* __restrict__ ag1, const float* __restrict__ ag2,
    float* __restrict__ hout)
{
  long gid = (long)blockIdx.x*256 + threadIdx.x;   // N*128
  int n = (int)(gid >> 7);
  float res = tval[n*4+0]*ag0[gid] + tval[n*4+1]*ag1[gid] + tval[n*4+2]*ag2[gid];
  hout[gid] = 0.5f*res*(1.f+erff(res*0.70710678118654752f));
}

__global__ __launch_bounds__(256) void lnf_kernel(
    const float* __restrict__ trans, const void* __restrict__ x, const int* __restrict__ flags,
    const int* __restrict__ nt, const float* __restrict__ wcf, void* __restrict__ outv)
{
  int wave = threadIdx.x >> 6, lane = threadIdx.x & 63;
  int n = blockIdx.x*4 + wave;
  int j = lane*2;
  int xf = flags[0];
  int t = nt[n];
  float alpha = 1.f/(1.f+expf(-wcf[W_SKIP+t]));
  long base = (long)n*128 + j;
  float y0 = alpha*trans[base]   + (1.f-alpha)*ldx(x, base,   xf);
  float y1 = alpha*trans[base+1] + (1.f-alpha)*ldx(x, base+1, xf);
  float mu = wredsum(y0+y1) * (1.f/128.f);
  float d0 = y0-mu, d1 = y1-mu;
  float var = wredsum(d0*d0+d1*d1) * (1.f/128.f);
  float inv = rsqrtf(var + 1e-5f);
  float o0 = d0*inv*wcf[W_LNG + t*128+j]   + wcf[W_LNB + t*128+j];
  float o1 = d1*inv*wcf[W_LNG + t*128+j+1] + wcf[W_LNB + t*128+j+1];
  if (xf) {
    ((float*)outv)[base]   = o0;
    ((float*)outv)[base+1] = o1;
  } else {
    unsigned o = (unsigned)f2bf(o0) | ((unsigned)f2bf(o1)<<16);
    *reinterpret_cast<unsigned*>(((u16*)outv)+base) = o;
  }
}

// ---------------------------------------------------------------------------
extern "C" void kernel_launch(void* const* d_in, const int* in_sizes, int n_in,
                              void* d_out, int out_size, void* d_ws, size_t ws_size,
                              hipStream_t stream) {
  char* w = (char*)d_ws;
  int*      flags = (int*)     (w + OFF_FLAGS);
  float*    wcf   = (float*)   (w + OFF_WCF);
  int*      nt32  = (int*)     (w + OFF_NT32);
  int*      ei32  = (int*)     (w + OFF_EI32);
  int*      et32  = (int*)     (w + OFF_ET32);
  int*      perm  = (int*)     (w + OFF_PERM);
  int*      pcnt  = (int*)     (w + OFF_PCNT);
  int*      pc2   = (int*)     (w + OFF_PCNT + 128);
  float*    raT   = (float*)   (w + OFF_TVAL);   // raT -> satt -> tval (disjoint)
  float*    satt  = (float*)   (w + OFF_TVAL);
  float*    tval  = (float*)   (w + OFF_TVAL);
  int*      nperm = (int*)     (w + OFF_NPERM);
  float*    logits= (float*)   (w + OFF_LOG);
  unsigned* mxkey = (unsigned*)(w + OFF_LOG + 5120000);
  float*    sumex = (float*)   (w + OFF_LOG + 5760000);
  int*      deg   = (int*)     (w + OFF_LOG + 6400000);
  float*    MT    = (float*)   (w + OFF_LOG);            // overlays dead softmax scratch
  float*    ckb   = (float*)   (w + OFF_LOG + 786432);
  float*    qn    = (float*)   (w + OFF_QN);
  float*    ag0   = (float*)   (w + OFF_QN);
  float*    trans = (float*)   (w + OFF_QN);
  float*    kn    = (float*)   (w + OFF_KN);
  float*    ag1   = (float*)   (w + OFF_KN);
  float*    vn    = (float*)   (w + OFF_VN);
  float*    ag2   = (float*)   (w + OFF_VN);
  float*    qlin  = (float*)   (w + OFF_QLIN);
  float*    hbuf  = (float*)   (w + OFF_QLIN);
  float*    qtrb  = (float*)   (w + OFF_QTR);
  float*    vp    = (float*)   (w + OFF_QTR);

  // s0: dtype detect + canonicalize
  detect_kernel<<<1,256,0,stream>>>((const u16*)d_in[0], (const int*)d_in[1], flags);
  FPtrs fp;
  fp.p[0]=d_in[5];  fp.p[1]=d_in[7];  fp.p[2]=d_in[9];  fp.p[3]=d_in[11];
  fp.p[4]=d_in[6];  fp.p[5]=d_in[8];  fp.p[6]=d_in[10]; fp.p[7]=d_in[12];
  fp.p[8]=d_in[13]; fp.p[9]=d_in[14]; fp.p[10]=d_in[15];fp.p[11]=d_in[16];
  fp.p[12]=d_in[17];fp.p[13]=d_in[18];fp.p[14]=d_in[19];fp.p[15]=d_in[20];
  fp.p[16]=d_in[21];fp.p[17]=d_in[22];fp.p[18]=d_in[23];fp.p[19]=d_in[24];
  convf_kernel<<<1451,256,0,stream>>>(flags, fp, wcf);
  idxconv_kernel<<<3907,256,0,stream>>>(flags, (const int*)d_in[1],
                                        (const int*)d_in[2], (const int*)d_in[3],
                                        nt32, ei32, et32);
  // s0.7: node-type perm (LDS-histogram sort)
  pinit_kernel<<<157,256,0,stream>>>(perm, pcnt);
  cnt_kernel  <<<157,256,0,stream>>>(nt32, N_, T_, pcnt);
  pofs_kernel <<<1,64,0,stream>>>(pcnt);
  scat_kernel <<<157,256,0,stream>>>(nt32, N_, T_, pcnt+8, pcnt+4, perm);
  // s0.8: edge-type perm over first N edges (LDS-histogram sort)
  einit_kernel<<<158,256,0,stream>>>(nperm, pc2);
  cnt_kernel  <<<157,256,0,stream>>>(et32, N_, R_, pc2);
  eofs_kernel <<<1,64,0,stream>>>(pc2);
  scat_kernel <<<157,256,0,stream>>>(et32, N_, R_, pc2+10, pc2+5, nperm);
  // s1: raT
  prepA_kernel<<<80,256,0,stream>>>(wcf, raT);

  // s2: q/k/v typed projections (one batched dispatch)
  P3 xin; xin.a[0]=(const float*)d_in[0]; xin.a[1]=xin.a[0]; xin.a[2]=xin.a[0];
  gemmt_kernel<<<dim3(628,3),256,0,stream>>>(xin, flags, 0,
      wcf+W_QW, 49152, wcf+W_QB, 384, perm, nt32, 0, nullptr, nullptr, 0, nullptr,
      qn, 5120000);
  // s3: qlin
  gemmt_kernel<<<dim3(625,1),256,0,stream>>>(xin, flags, 0,
      wcf+W_WQ, 0, wcf+W_BQ, 0, nullptr, nullptr, 0, nullptr, nullptr, 0, nullptr,
      qlin, 0);

  // s5.5: init softmax accumulators
  init_kernel<<<625,256,0,stream>>>(mxkey, sumex, deg);

  // s6: per-relation qtr (gemmbd) + edge pass
  for (int r=0; r<R_; ++r) {
    gemmbd_kernel<<<625,256,0,stream>>>(qn, raT + r*4096, 0, nullptr, nullptr, nullptr, qtrb);
    epass_kernel<<<5000,256,0,stream>>>(kn, qtrb, wcf, ei32, et32, r, logits, mxkey, deg);
  }
  // s7: exp + segment-sum
  eexp_kernel<<<5000,256,0,stream>>>(ei32, logits, mxkey, sumex);

  // s7.5: vp[n] = vn[src[n]] @ BD(rel_msg[et[n]])  (edge-type-sorted blocks)
  gemmbd_kernel<<<630,256,0,stream>>>(vn, wcf+W_RMSG, 1, nperm, ei32, et32, vp);

  // s7.75: satt = deg·ex/sumex  (softmax scratch dead after this)
  satt_kernel<<<625,256,0,stream>>>(ei32, logits, sumex, deg, satt);

  // s8.25: MT/ck into dead softmax region
  prepB_kernel<<<dim3(128,3),128,0,stream>>>(wcf, MT, ckb);

  // s8.5: ag_k = pow_k(vp)·satt @ WMk[k]  (powmode gemmt, batched k)
  P3 xvp; xvp.a[0]=vp; xvp.a[1]=vp; xvp.a[2]=vp;
  gemmt_kernel<<<dim3(625,3),256,0,stream>>>(xvp, flags, 1,
      wcf+W_WMK, 16384, nullptr, 0, nullptr, nullptr, 0, nullptr, nullptr, 1, satt,
      ag0, 5120000);

  // s9: gate scalars (dot-mode gemmt)
  P3 xag; xag.a[0]=ag0; xag.a[1]=ag1; xag.a[2]=ag2;
  gemmt_kernel<<<dim3(625,3),256,0,stream>>>(xag, flags, 1,
      MT, 16384, nullptr, 0, nullptr, nullptr, 1, qlin, ckb, 0, nullptr,
      tval, 0);

  // s10: mix + gelu -> hbuf (overlays qlin)
  gatemix_kernel<<<20000,256,0,stream>>>(tval, ag0, ag1, ag2, hbuf);

  // s11: trans = typed(h, a_w, a_b)
  P3 xh; xh.a[0]=hbuf; xh.a[1]=hbuf; xh.a[2]=hbuf;
  gemmt_kernel<<<dim3(628,1),256,0,stream>>>(xh, flags, 1,
      wcf+W_AW, 0, wcf+W_AB, 0, perm, nt32, 0, nullptr, nullptr, 0, nullptr,
      trans, 0);

  // s12: skip-mix + per-type LayerNorm -> out
  lnf_kernel<<<10000,256,0,stream>>>(trans, d_in[0], flags, nt32, wcf, d_out);

  (void)in_sizes; (void)n_in; (void)out_size; (void)ws_size;
}

// Round 9
// 647.180 us; speedup vs baseline: 2.4734x; 1.0174x over previous
//
#include <hip/hip_runtime.h>

// GeneralConv_30820685316781 — f32 build, round 9: gemmt2 (128x128 tile, 8x8/thread, k-major A)
#define N_ 40000
#define E_ 320000
#define D_ 128
#define H_ 4
#define T_ 3
#define R_ 5

typedef unsigned short u16;

__device__ __forceinline__ float bf2f(u16 h){ return __uint_as_float(((unsigned)h)<<16); }
__device__ __forceinline__ u16 f2bf(float f){
  unsigned u = __float_as_uint(f);
  u += 0x7fffu + ((u>>16)&1u);     // RNE
  return (u16)(u>>16);
}
__device__ __forceinline__ unsigned fmono(float f){
  unsigned u = __float_as_uint(f);
  return (u>>31) ? ~u : (u | 0x80000000u);
}
__device__ __forceinline__ float monof(unsigned u){
  return (u>>31) ? __uint_as_float(u & 0x7fffffffu) : __uint_as_float(~u);
}
__device__ __forceinline__ float ldx(const void* p, long i, int f32){
  return f32 ? ((const float*)p)[i] : bf2f(((const u16*)p)[i]);
}
__device__ __forceinline__ float wredsum(float v){
  #pragma unroll
  for (int m=32;m;m>>=1) v += __shfl_xor(v, m, 64);
  return v;
}

// wcf element offsets (f32 canonical weight buffer)
#define W_QW 0
#define W_KW 49152
#define W_VW 98304
#define W_AW 147456
#define W_QB 196608
#define W_KB 196992
#define W_VB 197376
#define W_AB 197760
#define W_PRI 198144
#define W_RATT 198164
#define W_RMSG 218644
#define W_WMK 239124
#define W_WAK 288276
#define W_WQ 337428
#define W_BQ 353812
#define W_WKL 353940
#define W_BKL 370324
#define W_SKIP 370452
#define W_LNG 370455
#define W_LNB 370839
#define W_TOT 371223

// ---- workspace layout (bytes). Peak 115,248,896 < proven 115,365,376. ----
#define OFF_FLAGS 0ul
#define OFF_WCF   512ul
#define OFF_NT32  1485824ul
#define OFF_EI32  1646080ul
#define OFF_ET32  4206592ul
#define OFF_PERM  5486592ul    // node perm: 40448 ints, 128-aligned type groups, -1 pad
#define OFF_PCNT  5648384ul    // pcnt[12] | pc2[16] at +128
#define OFF_TVAL  5648896ul    // raT 80KB (s1-s6) | satt/tval 640KB (s7.75+)
#define OFF_NPERM 5730816ul    // 40320 ints, edge-type-sorted first-N edges (s0.8-s7.5)
#define OFF_LOG   6288896ul    // logits 5.12M | mxkey .64M | sumex .64M | deg .16M ; MT+ck overlay after satt
#define OFF_QN    12848896ul   // qn -> ag0 -> trans
#define OFF_KN    33328896ul   // kn -> ag1
#define OFF_VN    53808896ul   // vn -> ag2
#define OFF_QLIN  74288896ul   // qlin -> hbuf
#define OFF_QTR   94768896ul   // qtrb (s6) -> vp (s7.5-s8)

// ---------------------------------------------------------------------------
__global__ __launch_bounds__(256) void detect_kernel(
    const u16* __restrict__ xs, const int* __restrict__ nt, int* __restrict__ flags)
{
  __shared__ int sBig, sZero, sNz;
  int tid = threadIdx.x;
  if (tid==0){ sBig=0; sZero=0; sNz=0; }
  __syncthreads();
  int big=0, zc=0;
  for (int i=tid; i<1024; i+=256) {
    u16 v = xs[2*i];
    int e = (v>>7)&0xFF;
    big += (e >= 200);
    zc  += (v == 0);
  }
  int nz=0;
  for (int i=tid; i<1024; i+=256) nz += (nt[2*i+1] != 0);
  atomicAdd(&sBig, big); atomicAdd(&sZero, zc); atomicAdd(&sNz, nz);
  __syncthreads();
  if (tid==0) {
    flags[0] = (sBig > 64) || (sZero > 900);
    flags[1] = (sNz == 0);
  }
}

struct FPtrs { const void* p[20]; };
__global__ __launch_bounds__(256) void convf_kernel(
    const int* __restrict__ flags, FPtrs ptrs, float* __restrict__ wcf)
{
  const int start[21] = {0,49152,98304,147456,196608,196992,197376,197760,198144,
    198164,218644,239124,288276,337428,353812,353940,370324,370452,370455,370839,371223};
  int i = blockIdx.x*256 + threadIdx.x;
  if (i >= W_TOT) return;
  int arr = 0;
  #pragma unroll
  for (int a=1; a<20; ++a) arr += (i >= start[a]);
  int local = i - start[arr];
  wcf[i] = ldx(ptrs.p[arr], local, flags[0]);
}

__global__ __launch_bounds__(256) void idxconv_kernel(
    const int* __restrict__ flags,
    const int* __restrict__ nt, const int* __restrict__ ei, const int* __restrict__ et,
    int* __restrict__ nt32, int* __restrict__ ei32, int* __restrict__ et32)
{
  int i = blockIdx.x*256 + threadIdx.x;
  if (i >= 1000000) return;
  int w = flags[1] ? 2 : 1;
  if (i < 40000)        nt32[i] = nt[(long)i*w];
  else if (i < 680000)  { int j=i-40000;  ei32[j] = ei[(long)j*w]; }
  else                  { int j=i-680000; et32[j] = et[(long)j*w]; }
}

// ---- low-contention counting sort (generic, ntypes<=8) ----
__global__ __launch_bounds__(256) void pinit_kernel(int* __restrict__ perm, int* __restrict__ pc){
  int i = blockIdx.x*256 + threadIdx.x;
  if (i < 40448) perm[i] = -1;
  if (i < 12) pc[i] = 0;
}
__global__ __launch_bounds__(256) void einit_kernel(int* __restrict__ nperm, int* __restrict__ pc2){
  int i = blockIdx.x*256 + threadIdx.x;
  if (i < 40320) nperm[i] = -1;
  if (i < 16) pc2[i] = 0;
}
__global__ __launch_bounds__(256) void cnt_kernel(
    const int* __restrict__ keys, int n, int ntypes, int* __restrict__ gcnt)
{
  __shared__ int lh[8];
  if (threadIdx.x < ntypes) lh[threadIdx.x] = 0;
  __syncthreads();
  int i = blockIdx.x*256 + threadIdx.x;
  if (i < n) atomicAdd(&lh[keys[i]], 1);
  __syncthreads();
  if (threadIdx.x < ntypes && lh[threadIdx.x])
    atomicAdd(&gcnt[threadIdx.x], lh[threadIdx.x]);
}
// node groups 128-aligned (gemmt2 has 128-row blocks -> must be type-uniform)
__global__ void pofs_kernel(int* __restrict__ pc){
  if (threadIdx.x==0 && blockIdx.x==0) {
    pc[8] = 0;
    pc[9] = (pc[0]+127)&~127;
    pc[10] = pc[9] + ((pc[1]+127)&~127);
  }
}
// edge groups 64-aligned (gemmbd has 64-row blocks)
__global__ void eofs_kernel(int* __restrict__ pc2){
  if (threadIdx.x==0 && blockIdx.x==0) {
    pc2[10] = 0;
    #pragma unroll
    for (int r=1;r<R_;++r) pc2[10+r] = pc2[10+r-1] + ((pc2[r-1]+63)&~63);
  }
}
__global__ __launch_bounds__(256) void scat_kernel(
    const int* __restrict__ keys, int n, int ntypes,
    const int* __restrict__ ofs, int* __restrict__ fill, int* __restrict__ perm)
{
  __shared__ int lh[8];
  __shared__ int lbase[8];
  if (threadIdx.x < ntypes) lh[threadIdx.x] = 0;
  __syncthreads();
  int i = blockIdx.x*256 + threadIdx.x;
  int t = 0, rank = 0;
  bool ok = (i < n);
  if (ok) { t = keys[i]; rank = atomicAdd(&lh[t], 1); }
  __syncthreads();
  if (threadIdx.x < ntypes)
    lbase[threadIdx.x] = lh[threadIdx.x] ? atomicAdd(&fill[threadIdx.x], lh[threadIdx.x]) : 0;
  __syncthreads();
  if (ok) perm[ofs[t] + lbase[t] + rank] = i;
}

__global__ __launch_bounds__(256) void init_kernel(
    unsigned* __restrict__ mxkey, float* __restrict__ sumex, int* __restrict__ deg)
{
  int i = blockIdx.x*256 + threadIdx.x;   // 625*256 = N*H
  mxkey[i] = fmono(-1e30f);
  sumex[i] = 0.f;
  if (i < N_) deg[i] = 0;
}

// prepA: raT[r][h][m][d] = rel_att[r][h][d][m]
__global__ __launch_bounds__(256) void prepA_kernel(
    const float* __restrict__ wcf, float* __restrict__ raT)
{
  int i = blockIdx.x*256 + threadIdx.x;
  if (i >= 20480) return;
  int d = i & 31, m = (i>>5) & 31, rh = i >> 10;
  raT[i] = wcf[W_RATT + (rh*32 + d)*32 + m];
}

// prepB: MT[k][i*128+col] = sum_j Wak_k[col,j]*Wkl[i,j];  ck[k][col] = sum_j Wak_k[col,j]*bkl[j]
__global__ __launch_bounds__(128) void prepB_kernel(
    const float* __restrict__ wcf, float* __restrict__ MT, float* __restrict__ ck)
{
  int col = threadIdx.x, i = blockIdx.x, k = blockIdx.y;
  const float* wak = wcf + W_WAK + k*16384 + col*128;
  const float* wkl = wcf + W_WKL + i*128;
  float acc = 0.f, accC = 0.f;
  #pragma unroll 8
  for (int j=0;j<128;++j) {
    float a = wak[j];
    acc  += a * wkl[j];
    if (i==0) accC += a * wcf[W_BKL + j];
  }
  MT[k*16384 + i*128 + col] = acc;
  if (i==0) ck[k*128 + col] = accC;
}

// ---------------------------------------------------------------------------
// gemmt2: LDS-tiled f32 GEMM, block = 128 rows x 128 cols, thread = 8 rows x (4+4) cols.
// A staged k-major (stride 132, conflict-free reads); W staged [k][col] (2-way, free).
// Per-y config: X pointer, weight/bias offsets, typed flag. powmode/dotmode as before.
struct GC4 { const float* x[4]; int woff[4]; int boff[4]; int typed[4]; };
__global__ __launch_bounds__(256) void gemmt2_kernel(
    GC4 cfg, const int* __restrict__ flags, int xmode,
    const float* __restrict__ Wsrc,
    const int* __restrict__ perm, const int* __restrict__ nt,
    int dotmode, const float* __restrict__ qlin, const float* __restrict__ ck,
    int powmode, const float* __restrict__ sattp,
    float* __restrict__ out, long yostride)
{
  __shared__ float As[32*132];    // k-major: As[k*132 + row], 16.9 KB
  __shared__ float Ws[4096];      // Ws[k*128 + col], 16 KB
  __shared__ int ridx[128];
  __shared__ int tblk_s;
  int tid = threadIdx.x;
  int y = blockIdx.y;
  int row0 = blockIdx.x*128;
  if (tid < 128) {
    int rr = row0 + tid;
    int rg = perm ? perm[rr] : (rr < N_ ? rr : -1);
    ridx[tid] = rg;
    if (tid==0) tblk_s = (perm && nt && rg>=0) ? nt[rg] : 0;
  }
  __syncthreads();
  if (ridx[0] < 0) return;        // fully padded block (128-aligned groups -> uniform)
  int tblk = cfg.typed[y] ? tblk_s : 0;
  const float* Wg = Wsrc + cfg.woff[y] + tblk*16384;
  const void* X = (const void*)cfg.x[y];
  int xf = xmode ? 1 : flags[0];

  int rg_ = tid >> 4;             // 16 row-groups of 8 rows
  int cg  = tid & 15;             // 16 col-groups; cols cg*4..+3 and 64+cg*4..+3
  int rowb = rg_*8;
  float acc[8][8];
  #pragma unroll
  for (int r=0;r<8;++r)
    #pragma unroll
    for (int c=0;c<8;++c) acc[r][c]=0.f;

  int sr = tid >> 1;              // staging row 0..127
  int sh = (tid & 1) * 16;        // staging k offset 0/16
  int srow = ridx[sr];

  for (int kc=0;kc<4;++kc) {
    __syncthreads();
    // stage A (128 rows x 32 k), k-major
    {
      float v[16];
      if (srow < 0) {
        #pragma unroll
        for (int j=0;j<16;++j) v[j]=0.f;
      } else if (powmode) {
        const float4* s4 = reinterpret_cast<const float4*>((const float*)X + (long)srow*128 + kc*32 + sh);
        float4 q0=s4[0],q1=s4[1],q2=s4[2],q3=s4[3];
        float tv[16] = {q0.x,q0.y,q0.z,q0.w,q1.x,q1.y,q1.z,q1.w,
                        q2.x,q2.y,q2.z,q2.w,q3.x,q3.y,q3.z,q3.w};
        float sc = sattp[srow*4 + kc];   // h == kc
        #pragma unroll
        for (int j=0;j<16;++j) {
          float vv = tv[j]; float a;
          if (y==0)      a = vv*sc;
          else if (y==1) a = vv*vv*sc;
          else { float a3 = vv*vv*vv*sc;
                 a = (a3==0.f) ? 0.f : copysignf(cbrtf(fabsf(a3)+1e-18f), a3); }
          v[j] = a;
        }
      } else if (xf) {
        const float4* s4 = reinterpret_cast<const float4*>((const float*)X + (long)srow*128 + kc*32 + sh);
        float4 q0=s4[0],q1=s4[1],q2=s4[2],q3=s4[3];
        v[0]=q0.x;v[1]=q0.y;v[2]=q0.z;v[3]=q0.w; v[4]=q1.x;v[5]=q1.y;v[6]=q1.z;v[7]=q1.w;
        v[8]=q2.x;v[9]=q2.y;v[10]=q2.z;v[11]=q2.w; v[12]=q3.x;v[13]=q3.y;v[14]=q3.z;v[15]=q3.w;
      } else {
        const u16* s = (const u16*)X + (long)srow*128 + kc*32 + sh;
        #pragma unroll
        for (int j=0;j<16;++j) v[j] = bf2f(s[j]);
      }
      #pragma unroll
      for (int j=0;j<16;++j) As[(sh+j)*132 + sr] = v[j];
    }
    // stage W (contiguous 4096 f32 chunk)
    #pragma unroll
    for (int j=0;j<4;++j) {
      float4 v4 = *reinterpret_cast<const float4*>(Wg + kc*4096 + j*1024 + tid*4);
      *reinterpret_cast<float4*>(&Ws[j*1024 + tid*4]) = v4;
    }
    __syncthreads();
    // compute
    #pragma unroll
    for (int kq=0;kq<8;++kq) {
      #pragma unroll
      for (int i=0;i<4;++i) {
        int k = kq*4+i;
        float4 w0 = *reinterpret_cast<const float4*>(&Ws[k*128 + cg*4]);
        float4 w1 = *reinterpret_cast<const float4*>(&Ws[k*128 + 64 + cg*4]);
        float4 a0 = *reinterpret_cast<const float4*>(&As[k*132 + rowb]);
        float4 a1 = *reinterpret_cast<const float4*>(&As[k*132 + rowb + 4]);
        float av[8] = {a0.x,a0.y,a0.z,a0.w,a1.x,a1.y,a1.z,a1.w};
        float wv[8] = {w0.x,w0.y,w0.z,w0.w,w1.x,w1.y,w1.z,w1.w};
        #pragma unroll
        for (int r=0;r<8;++r)
          #pragma unroll
          for (int c=0;c<8;++c)
            acc[r][c] += av[r]*wv[c];
      }
    }
  }

  if (!dotmode) {
    float b[8] = {0,0,0,0,0,0,0,0};
    if (cfg.boff[y] >= 0) {
      const float* bp = Wsrc + cfg.boff[y] + tblk*128;
      #pragma unroll
      for (int c=0;c<4;++c) { b[c]=bp[cg*4+c]; b[4+c]=bp[64+cg*4+c]; }
    }
    #pragma unroll
    for (int r=0;r<8;++r) {
      int rowg = ridx[rowb + r];
      if (rowg < 0) continue;
      float4 o0 = {acc[r][0]+b[0], acc[r][1]+b[1], acc[r][2]+b[2], acc[r][3]+b[3]};
      float4 o1 = {acc[r][4]+b[4], acc[r][5]+b[5], acc[r][6]+b[6], acc[r][7]+b[7]};
      float* op = out + (long)y*yostride + (long)rowg*128;
      *reinterpret_cast<float4*>(op + cg*4)      = o0;
      *reinterpret_cast<float4*>(op + 64 + cg*4) = o1;
    }
  } else {
    float c0[8];
    #pragma unroll
    for (int c=0;c<4;++c) { c0[c]=ck[y*128+cg*4+c]; c0[4+c]=ck[y*128+64+cg*4+c]; }
    #pragma unroll
    for (int r=0;r<8;++r) {
      int rowg = ridx[rowb + r];
      float d = 0.f;
      if (rowg >= 0) {
        const float* qp = qlin + (long)rowg*128;
        #pragma unroll
        for (int c=0;c<4;++c) {
          d += (acc[r][c]  +c0[c])  *qp[cg*4+c];
          d += (acc[r][4+c]+c0[4+c])*qp[64+cg*4+c];
        }
      }
      #pragma unroll
      for (int m=8;m;m>>=1) d += __shfl_xor(d, m, 64);   // reduce 16 cg lanes
      if (cg==0 && rowg>=0) out[(long)rowg*4 + y] = 1.f/(1.f+expf(-d));
    }
  }
}

// ---------------------------------------------------------------------------
// gemmbd: block-diagonal (4 heads x 32x32) GEMM, 64 rows x 128 cols per block.
__global__ __launch_bounds__(256) void gemmbd_kernel(
    const float* __restrict__ X,
    const float* __restrict__ Wtab, int wsel,
    const int* __restrict__ perm, const int* __restrict__ gsrc, const int* __restrict__ et,
    float* __restrict__ out)
{
  __shared__ float As[64*152];    // [row][h*36 + m], bank-staggered
  __shared__ float Ws[4096];
  __shared__ int ridx[64];
  __shared__ int rsel_s;
  int tid = threadIdx.x;
  int row0 = blockIdx.x*64;
  if (tid < 64) {
    int rr = row0 + tid;
    int pe = perm ? perm[rr] : (rr < N_ ? rr : -1);
    ridx[tid] = pe;
    if (tid == 0) rsel_s = (wsel && pe >= 0) ? et[pe] : 0;
  }
  __syncthreads();
  if (ridx[0] < 0) return;
  const float* Wg = Wtab + (long)(wsel ? rsel_s : 0)*4096;
  #pragma unroll
  for (int j=0;j<4;++j)
    *reinterpret_cast<float4*>(&Ws[j*1024 + tid*4]) =
      *reinterpret_cast<const float4*>(Wg + j*1024 + tid*4);
  {
    int sar = tid >> 2, sh = tid & 3;
    int pe_s = ridx[sar];
    int arow = (pe_s < 0) ? -1 : (gsrc ? gsrc[pe_s] : pe_s);
    float* dst = &As[sar*152 + sh*36];
    if (arow < 0) {
      #pragma unroll
      for (int j=0;j<8;++j) *reinterpret_cast<float4*>(dst + j*4) = float4{0.f,0.f,0.f,0.f};
    } else {
      const float4* s4 = reinterpret_cast<const float4*>(X + (long)arow*128 + sh*32);
      #pragma unroll
      for (int j=0;j<8;++j) *reinterpret_cast<float4*>(dst + j*4) = s4[j];
    }
  }
  __syncthreads();
  int rg_ = tid >> 5, cg = tid & 31;
  int h = cg >> 3, c4 = (cg & 7)*4;
  float acc[8][4];
  #pragma unroll
  for (int r=0;r<8;++r){ acc[r][0]=0.f; acc[r][1]=0.f; acc[r][2]=0.f; acc[r][3]=0.f; }
  #pragma unroll
  for (int mq=0;mq<8;++mq) {
    float wv[4][4];
    #pragma unroll
    for (int i=0;i<4;++i) {
      float4 wt = *reinterpret_cast<const float4*>(&Ws[h*1024 + (mq*4+i)*32 + c4]);
      wv[i][0]=wt.x; wv[i][1]=wt.y; wv[i][2]=wt.z; wv[i][3]=wt.w;
    }
    #pragma unroll
    for (int r=0;r<8;++r) {
      float4 a4 = *reinterpret_cast<const float4*>(&As[(rg_*8+r)*152 + h*36 + mq*4]);
      float av[4] = {a4.x,a4.y,a4.z,a4.w};
      #pragma unroll
      for (int i=0;i<4;++i) {
        acc[r][0]+=av[i]*wv[i][0]; acc[r][1]+=av[i]*wv[i][1];
        acc[r][2]+=av[i]*wv[i][2]; acc[r][3]+=av[i]*wv[i][3];
      }
    }
  }
  #pragma unroll
  for (int r=0;r<8;++r) {
    int pe = ridx[rg_*8+r];
    if (pe < 0) continue;
    float4 o = {acc[r][0],acc[r][1],acc[r][2],acc[r][3]};
    *reinterpret_cast<float4*>(out + (long)pe*128 + h*32 + c4) = o;
  }
}

// ---------------------------------------------------------------------------
__global__ __launch_bounds__(256) void epass_kernel(
    const float* __restrict__ kn, const float* __restrict__ qtr, const float* __restrict__ wcf,
    const int* __restrict__ ei, const int* __restrict__ et, int rsel,
    float* __restrict__ logits, unsigned* __restrict__ mxkey, int* __restrict__ deg)
{
  int gid = blockIdx.x*256 + threadIdx.x;   // E*H
  int e = gid >> 2, h = gid & 3;
  if (et[e] != rsel) return;
  int s = ei[e], t = ei[E_+e];
  const float4* ka = reinterpret_cast<const float4*>(kn + (long)s*128 + h*32);
  const float4* qa = reinterpret_cast<const float4*>(qtr + (long)t*128 + h*32);
  float acc = 0.f;
  #pragma unroll
  for (int i=0;i<8;++i) {
    float4 a = ka[i], b = qa[i];
    acc += a.x*b.x + a.y*b.y + a.z*b.z + a.w*b.w;
  }
  float lg = acc * wcf[W_PRI + rsel*H_+h] * 0.17677669529663687f;
  logits[gid] = lg;
  atomicMax(mxkey + t*H_+h, fmono(lg));
  if (h==0) atomicAdd(deg + t, 1);
}

__global__ __launch_bounds__(256) void eexp_kernel(
    const int* __restrict__ ei, float* __restrict__ logits,
    const unsigned* __restrict__ mxkey, float* __restrict__ sumex)
{
  int gid = blockIdx.x*256 + threadIdx.x;
  int e = gid >> 2, h = gid & 3;
  int t = ei[E_+e];
  float d = fminf(logits[gid] - monof(mxkey[t*H_+h]), 0.f);
  float ex = expf(d);
  if (e < N_) logits[gid] = ex;    // only first-N edges' ex are ever read (satt)
  atomicAdd(sumex + t*H_+h, ex);
}

// satt[n*4+h] = deg[n] * ex[n*4+h] / (sumex[tgt[n]*4+h] + 1e-16)
__global__ __launch_bounds__(256) void satt_kernel(
    const int* __restrict__ ei, const float* __restrict__ ex, const float* __restrict__ sumex,
    const int* __restrict__ deg, float* __restrict__ satt)
{
  int i = blockIdx.x*256 + threadIdx.x;   // N*H
  int n = i >> 2, h = i & 3;
  int t = ei[E_+n];
  satt[i] = (float)deg[n] * ex[i] / (sumex[t*H_+h] + 1e-16f);
}

// gatemix: res = sum_k t_k·ag_k; h = gelu_exact(res)
__global__ __launch_bounds__(256) void gatemix_kernel(
    const float* __restrict__ tval,
    const float* __restrict__ ag0, const float* __restrict__ ag1, const float* __restrict__ ag2,
    float* __restrict__ hout)
{
  long gid = (long)blockIdx.x*256 + threadIdx.x;   // N*128
  int n = (int)(gid >> 7);
  float res = tval[n*4+0]*ag0[gid] + tval[n*4+1]*ag1[gid] + tval[n*4+2]*ag2[gid];
  hout[gid] = 0.5f*res*(1.f+erff(res*0.70710678118654752f));
}

__global__ __launch_bounds__(256) void lnf_kernel(
    const float* __restrict__ trans, const void* __restrict__ x, const int* __restrict__ flags,
    const int* __restrict__ nt, const float* __restrict__ wcf, void* __restrict__ outv)
{
  int wave = threadIdx.x >> 6, lane = threadIdx.x & 63;
  int n = blockIdx.x*4 + wave;
  int j = lane*2;
  int xf = flags[0];
  int t = nt[n];
  float alpha = 1.f/(1.f+expf(-wcf[W_SKIP+t]));
  long base = (long)n*128 + j;
  float y0 = alpha*trans[base]   + (1.f-alpha)*ldx(x, base,   xf);
  float y1 = alpha*trans[base+1] + (1.f-alpha)*ldx(x, base+1, xf);
  float mu = wredsum(y0+y1) * (1.f/128.f);
  float d0 = y0-mu, d1 = y1-mu;
  float var = wredsum(d0*d0+d1*d1) * (1.f/128.f);
  float inv = rsqrtf(var + 1e-5f);
  float o0 = d0*inv*wcf[W_LNG + t*128+j]   + wcf[W_LNB + t*128+j];
  float o1 = d1*inv*wcf[W_LNG + t*128+j+1] + wcf[W_LNB + t*128+j+1];
  if (xf) {
    ((float*)outv)[base]   = o0;
    ((float*)outv)[base+1] = o1;
  } else {
    unsigned o = (unsigned)f2bf(o0) | ((unsigned)f2bf(o1)<<16);
    *reinterpret_cast<unsigned*>(((u16*)outv)+base) = o;
  }
}

// ---------------------------------------------------------------------------
extern "C" void kernel_launch(void* const* d_in, const int* in_sizes, int n_in,
                              void* d_out, int out_size, void* d_ws, size_t ws_size,
                              hipStream_t stream) {
  char* w = (char*)d_ws;
  int*      flags = (int*)     (w + OFF_FLAGS);
  float*    wcf   = (float*)   (w + OFF_WCF);
  int*      nt32  = (int*)     (w + OFF_NT32);
  int*      ei32  = (int*)     (w + OFF_EI32);
  int*      et32  = (int*)     (w + OFF_ET32);
  int*      perm  = (int*)     (w + OFF_PERM);
  int*      pcnt  = (int*)     (w + OFF_PCNT);
  int*      pc2   = (int*)     (w + OFF_PCNT + 128);
  float*    raT   = (float*)   (w + OFF_TVAL);   // raT -> satt/tval (disjoint lifetimes)
  float*    satt  = (float*)   (w + OFF_TVAL);
  float*    tval  = (float*)   (w + OFF_TVAL);
  int*      nperm = (int*)     (w + OFF_NPERM);
  float*    logits= (float*)   (w + OFF_LOG);
  unsigned* mxkey = (unsigned*)(w + OFF_LOG + 5120000);
  float*    sumex = (float*)   (w + OFF_LOG + 5760000);
  int*      deg   = (int*)     (w + OFF_LOG + 6400000);
  float*    MT    = (float*)   (w + OFF_LOG);            // overlays dead softmax scratch
  float*    ckb   = (float*)   (w + OFF_LOG + 786432);
  float*    qn    = (float*)   (w + OFF_QN);
  float*    ag0   = (float*)   (w + OFF_QN);
  float*    trans = (float*)   (w + OFF_QN);
  float*    kn    = (float*)   (w + OFF_KN);
  float*    ag1   = (float*)   (w + OFF_KN);
  float*    vn    = (float*)   (w + OFF_VN);
  float*    ag2   = (float*)   (w + OFF_VN);
  float*    qlin  = (float*)   (w + OFF_QLIN);
  float*    hbuf  = (float*)   (w + OFF_QLIN);
  float*    qtrb  = (float*)   (w + OFF_QTR);
  float*    vp    = (float*)   (w + OFF_QTR);

  // s0: dtype detect + canonicalize
  detect_kernel<<<1,256,0,stream>>>((const u16*)d_in[0], (const int*)d_in[1], flags);
  FPtrs fp;
  fp.p[0]=d_in[5];  fp.p[1]=d_in[7];  fp.p[2]=d_in[9];  fp.p[3]=d_in[11];
  fp.p[4]=d_in[6];  fp.p[5]=d_in[8];  fp.p[6]=d_in[10]; fp.p[7]=d_in[12];
  fp.p[8]=d_in[13]; fp.p[9]=d_in[14]; fp.p[10]=d_in[15];fp.p[11]=d_in[16];
  fp.p[12]=d_in[17];fp.p[13]=d_in[18];fp.p[14]=d_in[19];fp.p[15]=d_in[20];
  fp.p[16]=d_in[21];fp.p[17]=d_in[22];fp.p[18]=d_in[23];fp.p[19]=d_in[24];
  convf_kernel<<<1451,256,0,stream>>>(flags, fp, wcf);
  idxconv_kernel<<<3907,256,0,stream>>>(flags, (const int*)d_in[1],
                                        (const int*)d_in[2], (const int*)d_in[3],
                                        nt32, ei32, et32);
  // s0.7: node-type perm (128-aligned groups)
  pinit_kernel<<<159,256,0,stream>>>(perm, pcnt);
  cnt_kernel  <<<157,256,0,stream>>>(nt32, N_, T_, pcnt);
  pofs_kernel <<<1,64,0,stream>>>(pcnt);
  scat_kernel <<<157,256,0,stream>>>(nt32, N_, T_, pcnt+8, pcnt+4, perm);
  // s0.8: edge-type perm over first N edges (64-aligned groups)
  einit_kernel<<<158,256,0,stream>>>(nperm, pc2);
  cnt_kernel  <<<157,256,0,stream>>>(et32, N_, R_, pc2);
  eofs_kernel <<<1,64,0,stream>>>(pc2);
  scat_kernel <<<157,256,0,stream>>>(et32, N_, R_, pc2+10, pc2+5, nperm);
  // s1: raT
  prepA_kernel<<<80,256,0,stream>>>(wcf, raT);

  // s2: q/k/v/qlin projections in ONE y=4 dispatch (qn,kn,vn,qlin contiguous at stride 5.12M)
  GC4 cq;
  cq.x[0]=(const float*)d_in[0]; cq.x[1]=cq.x[0]; cq.x[2]=cq.x[0]; cq.x[3]=cq.x[0];
  cq.woff[0]=W_QW; cq.woff[1]=W_KW; cq.woff[2]=W_VW; cq.woff[3]=W_WQ;
  cq.boff[0]=W_QB; cq.boff[1]=W_KB; cq.boff[2]=W_VB; cq.boff[3]=W_BQ;
  cq.typed[0]=1; cq.typed[1]=1; cq.typed[2]=1; cq.typed[3]=0;
  gemmt2_kernel<<<dim3(316,4),256,0,stream>>>(cq, flags, 0, wcf, perm, nt32,
      0, nullptr, nullptr, 0, nullptr, qn, 5120000);

  // s5.5: init softmax accumulators
  init_kernel<<<625,256,0,stream>>>(mxkey, sumex, deg);

  // s6: per-relation qtr (gemmbd) + edge pass
  for (int r=0; r<R_; ++r) {
    gemmbd_kernel<<<625,256,0,stream>>>(qn, raT + r*4096, 0, nullptr, nullptr, nullptr, qtrb);
    epass_kernel<<<5000,256,0,stream>>>(kn, qtrb, wcf, ei32, et32, r, logits, mxkey, deg);
  }
  // s7: exp + segment-sum
  eexp_kernel<<<5000,256,0,stream>>>(ei32, logits, mxkey, sumex);

  // s7.5: vp[n] = vn[src[n]] @ BD(rel_msg[et[n]])  (edge-type-sorted blocks)
  gemmbd_kernel<<<630,256,0,stream>>>(vn, wcf+W_RMSG, 1, nperm, ei32, et32, vp);

  // s7.75: satt = deg·ex/sumex  (softmax scratch dead after this)
  satt_kernel<<<625,256,0,stream>>>(ei32, logits, sumex, deg, satt);

  // s8.25: MT/ck into dead softmax region
  prepB_kernel<<<dim3(128,3),128,0,stream>>>(wcf, MT, ckb);

  // s8.5: ag_k = pow_k(vp)·satt @ WMk[k]  (powmode, batched k)
  GC4 cp;
  cp.x[0]=vp; cp.x[1]=vp; cp.x[2]=vp; cp.x[3]=vp;
  cp.woff[0]=W_WMK; cp.woff[1]=W_WMK+16384; cp.woff[2]=W_WMK+32768; cp.woff[3]=0;
  cp.boff[0]=-1; cp.boff[1]=-1; cp.boff[2]=-1; cp.boff[3]=-1;
  cp.typed[0]=0; cp.typed[1]=0; cp.typed[2]=0; cp.typed[3]=0;
  gemmt2_kernel<<<dim3(313,3),256,0,stream>>>(cp, flags, 1, wcf, nullptr, nullptr,
      0, nullptr, nullptr, 1, satt, ag0, 5120000);

  // s9: gate scalars (dot-mode)
  GC4 cd;
  cd.x[0]=ag0; cd.x[1]=ag1; cd.x[2]=ag2; cd.x[3]=ag2;
  cd.woff[0]=0; cd.woff[1]=16384; cd.woff[2]=32768; cd.woff[3]=0;
  cd.boff[0]=-1; cd.boff[1]=-1; cd.boff[2]=-1; cd.boff[3]=-1;
  cd.typed[0]=0; cd.typed[1]=0; cd.typed[2]=0; cd.typed[3]=0;
  gemmt2_kernel<<<dim3(313,3),256,0,stream>>>(cd, flags, 1, MT, nullptr, nullptr,
      1, qlin, ckb, 0, nullptr, tval, 0);

  // s10: mix + gelu -> hbuf (overlays qlin; qlin dead after dot-mode)
  gatemix_kernel<<<20000,256,0,stream>>>(tval, ag0, ag1, ag2, hbuf);

  // s11: trans = typed(h, a_w, a_b)
  GC4 ct;
  ct.x[0]=hbuf; ct.x[1]=hbuf; ct.x[2]=hbuf; ct.x[3]=hbuf;
  ct.woff[0]=W_AW; ct.woff[1]=0; ct.woff[2]=0; ct.woff[3]=0;
  ct.boff[0]=W_AB; ct.boff[1]=-1; ct.boff[2]=-1; ct.boff[3]=-1;
  ct.typed[0]=1; ct.typed[1]=0; ct.typed[2]=0; ct.typed[3]=0;
  gemmt2_kernel<<<dim3(316,1),256,0,stream>>>(ct, flags, 1, wcf, perm, nt32,
      0, nullptr, nullptr, 0, nullptr, trans, 0);

  // s12: skip-mix + per-type LayerNorm -> out
  lnf_kernel<<<10000,256,0,stream>>>(trans, d_in[0], flags, nt32, wcf, d_out);

  (void)in_sizes; (void)n_in; (void)out_size; (void)ws_size;
}